// Round 11
// baseline (381.632 us; speedup 1.0000x reference)
//
#include <hip/hip_runtime.h>
#include <hip/hip_bf16.h>
#include <math.h>

#define V 100000
#define H 256
#define B 512

typedef __bf16 bf16x8 __attribute__((ext_vector_type(8)));
typedef float  f32x4  __attribute__((ext_vector_type(4)));

__device__ __forceinline__ unsigned short f32_bf16_rne(float x) {
    unsigned u = __float_as_uint(x);
    u += 0x7FFFu + ((u >> 16) & 1u);            // round-to-nearest-even
    return (unsigned short)(u >> 16);
}
__device__ __forceinline__ float bf16u_f32(unsigned short h) {
    return __uint_as_float(((unsigned)h) << 16);
}
__device__ __forceinline__ float fast_tanh(float x) {
    // tanh(x) = 1 - 2/(exp2(2x*log2e)+1); saturates correctly (proven r6)
    float e = __builtin_exp2f(x * 2.8853900817779268f);
    return 1.f - 2.f * __builtin_amdgcn_rcpf(e + 1.f);
}

// ---------------------------------------------------------------------------
// Kernel 1: GRU cell v3 (proven R9/R10). 256 blocks = 64 batch-groups x 4
// hidden-quarters. Writes h_new into d_out + B*V plus bf16 hi/lo planes.
// ---------------------------------------------------------------------------
__global__ __launch_bounds__(256) void gru_cell_v3(
    const int*   __restrict__ input,
    const float* __restrict__ hidden,
    const float* __restrict__ w_ih,
    const float* __restrict__ w_hh,
    const float* __restrict__ b_ih,
    const float* __restrict__ b_hh,
    float*       __restrict__ h_out,
    unsigned short* __restrict__ h_hi_p,   // may be null (fallback path)
    unsigned short* __restrict__ h_lo_p)
{
    const int gb  = blockIdx.x >> 2;
    const int q   = blockIdx.x & 3;
    const int b0  = gb * 8;
    const int j0  = q * 64;
    const int tid = threadIdx.x;
    const int jj  = tid & 63;
    const int bq  = tid >> 6;
    const int j   = j0 + jj;

    __shared__ float hs[8 * H];
    __shared__ int   idxs[8];
    #pragma unroll
    for (int i = 0; i < 2; ++i) {
        const int p = i * 256 + tid;
        reinterpret_cast<float4*>(hs)[p] =
            reinterpret_cast<const float4*>(hidden + (size_t)b0 * H)[p];
    }
    if (tid < 8) idxs[tid] = input[b0 + tid];
    __syncthreads();

    const int ba = bq * 2, bb = bq * 2 + 1;
    const int ia = idxs[ba], ib = idxs[bb];

    const float g_ra = w_ih[(size_t) j          * V + ia];
    const float g_rb = w_ih[(size_t) j          * V + ib];
    const float g_za = w_ih[(size_t)(j +     H) * V + ia];
    const float g_zb = w_ih[(size_t)(j +     H) * V + ib];
    const float g_na = w_ih[(size_t)(j + 2 * H) * V + ia];
    const float g_nb = w_ih[(size_t)(j + 2 * H) * V + ib];

    const float4* wr = reinterpret_cast<const float4*>(&w_hh[(size_t) j          * H]);
    const float4* wz = reinterpret_cast<const float4*>(&w_hh[(size_t)(j +     H) * H]);
    const float4* wn = reinterpret_cast<const float4*>(&w_hh[(size_t)(j + 2 * H) * H]);
    const float4* ha = reinterpret_cast<const float4*>(&hs[ba * H]);
    const float4* hb = reinterpret_cast<const float4*>(&hs[bb * H]);

    float ara = 0.f, aza = 0.f, ana = 0.f;
    float arb = 0.f, azb = 0.f, anb = 0.f;
    #pragma unroll 4
    for (int k = 0; k < H / 4; ++k) {
        const float4 a = wr[k];
        const float4 c = wz[k];
        const float4 d = wn[k];
        const float4 va = ha[k];
        const float4 vb = hb[k];
        ara += a.x * va.x + a.y * va.y + a.z * va.z + a.w * va.w;
        aza += c.x * va.x + c.y * va.y + c.z * va.z + c.w * va.w;
        ana += d.x * va.x + d.y * va.y + d.z * va.z + d.w * va.w;
        arb += a.x * vb.x + a.y * vb.y + a.z * vb.z + a.w * vb.w;
        azb += c.x * vb.x + c.y * vb.y + c.z * vb.z + c.w * vb.w;
        anb += d.x * vb.x + d.y * vb.y + d.z * vb.z + d.w * vb.w;
    }

    const float bir = b_ih[j], biz = b_ih[j + H], bin = b_ih[j + 2 * H];
    const float bhr = b_hh[j], bhz = b_hh[j + H], bhn = b_hh[j + 2 * H];

    #pragma unroll
    for (int s = 0; s < 2; ++s) {
        const float gi_r = (s ? g_rb : g_ra) + bir;
        const float gi_z = (s ? g_zb : g_za) + biz;
        const float gi_n = (s ? g_nb : g_na) + bin;
        const float h_r  = (s ? arb : ara) + bhr;
        const float h_z  = (s ? azb : aza) + bhz;
        const float h_n  = (s ? anb : ana) + bhn;
        const int   bg   = b0 + (s ? bb : ba);

        const float r = 1.f / (1.f + expf(-(gi_r + h_r)));
        const float z = 1.f / (1.f + expf(-(gi_z + h_z)));
        const float n = tanhf(gi_n + r * h_n);
        const float hprev = hs[(s ? bb : ba) * H + jj + j0];
        const float val = (1.f - z) * n + z * hprev;

        h_out[(size_t)bg * H + j] = val;
        if (h_hi_p != nullptr) {
            const unsigned short hh = f32_bf16_rne(val);
            h_hi_p[(size_t)bg * H + j] = hh;
            h_lo_p[(size_t)bg * H + j] = f32_bf16_rne(val - bf16u_f32(hh));
        }
    }
}

// ---------------------------------------------------------------------------
// Kernel 2 (multi-tile): logit = tanh(h_new @ w_out.T + b_out).
// Block = 64 batch x 4 vocab tiles of 128 (grid 1568, 4x fewer blocks):
//  - h A-fragments for ALL of K gathered once into 128 VGPRs (no per-chunk
//    loadA, no h LDS);
//  - w fp32 reg-staged into double-buffered LDS with in-kernel hi/lo split
//    (R4-proven convert): loads for chunk s+1 issued BEFORE compute(s),
//    convert+ds_write after (T14), ONE barrier per chunk;
//  - stores of tile t overlap the stage of tile t+1; per-block fixed costs
//    amortized 4x. No split_w prep kernel at all.
// VGPR ~230 -> 2 waves/SIMD; LDS 64 KB -> 2 blocks/CU.
// Fragment math / swizzle / epilogue identical to the verified r4-r10 path.
// ---------------------------------------------------------------------------
#define BM   64
#define BN   128
#define BK   64
#define NT   4
#define NVG  196           // vocab groups of NT*BN=512; 196*512 >= 100000
#define GRID2 (NVG * 8)    // 1568

__global__ __launch_bounds__(256, 2) void out_gemm_tiles(
    const float*          __restrict__ w_out,  // (V,H) fp32
    const unsigned short* __restrict__ hhi_g,  // (B,H) bf16 hi plane
    const unsigned short* __restrict__ hlo_g,  // (B,H) bf16 lo plane
    const float*          __restrict__ b_out,  // (V)
    float*                __restrict__ logit)  // (B,V)
{
    __shared__ unsigned short w_hi_s[2][BN * BK];   // 2 x 16 KB
    __shared__ unsigned short w_lo_s[2][BN * BK];   // 2 x 16 KB

    const int tid  = threadIdx.x;
    const int lane = tid & 63;
    const int wid  = tid >> 6;
    const int wm   = wid >> 1;      // batch half (0..1)
    const int wn   = wid & 1;       // vocab half (0..1)

    // bijective XCD-chunked swizzle: each XCD covers a contiguous vocab band,
    // all 8 batch-blocks of a band consecutive -> w L2-hit 7/8 times.
    const int bid = blockIdx.x;                    // 0..1567
    const int wg  = (bid & 7) * NVG + (bid >> 3);
    const int vg  = wg >> 3;                       // vocab group 0..195
    const int bx  = wg & 7;                        // batch block 0..7
    const int b0  = bx * BM;
    const int vbase = vg * (NT * BN);

    // ---- prologue: gather ALL h A-fragments (K=256) into registers --------
    bf16x8 aH[16], aL[16];   // [t*4 + i*2 + ks]
    #pragma unroll
    for (int t = 0; t < 4; ++t)
        #pragma unroll
        for (int i = 0; i < 2; ++i)
            #pragma unroll
            for (int ks = 0; ks < 2; ++ks) {
                const size_t ho = ((size_t)(b0 + wm * 32 + i * 16 + (lane & 15)) * H
                                   + t * BK + ks * 32 + (lane >> 4) * 8) * 2;
                aH[t * 4 + i * 2 + ks] = *reinterpret_cast<const bf16x8*>(
                                             reinterpret_cast<const char*>(hhi_g) + ho);
                aL[t * 4 + i * 2 + ks] = *reinterpret_cast<const bf16x8*>(
                                             reinterpret_cast<const char*>(hlo_g) + ho);
            }

    float4 wreg[8];
    auto load_w = [&](int v0n, int k0n) {
        #pragma unroll
        for (int i = 0; i < 8; ++i) {
            const int u   = i * 256 + tid;
            const int row = u >> 4;            // 0..127 local vocab row
            const int k4  = (u & 15) << 2;     // 0..60
            int vgl = v0n + row; if (vgl > V - 1) vgl = V - 1;  // clamp
            wreg[i] = *reinterpret_cast<const float4*>(
                          &w_out[(size_t)vgl * H + k0n + k4]);
        }
    };
    auto store_w = [&](unsigned short* whi_b, unsigned short* wlo_b) {
        #pragma unroll
        for (int i = 0; i < 8; ++i) {
            const int u   = i * 256 + tid;
            const int row = u >> 4;
            const int k4  = (u & 15) << 2;
            const int off = row * (BK * 2) + ((k4 * 2) ^ ((row & 7) << 4));
            const float f[4] = {wreg[i].x, wreg[i].y, wreg[i].z, wreg[i].w};
            unsigned short hv[4], lv[4];
            #pragma unroll
            for (int jj = 0; jj < 4; ++jj) {
                hv[jj] = f32_bf16_rne(f[jj]);
                lv[jj] = f32_bf16_rne(f[jj] - bf16u_f32(hv[jj]));
            }
            *reinterpret_cast<ushort4*>(reinterpret_cast<char*>(whi_b) + off) =
                make_ushort4(hv[0], hv[1], hv[2], hv[3]);
            *reinterpret_cast<ushort4*>(reinterpret_cast<char*>(wlo_b) + off) =
                make_ushort4(lv[0], lv[1], lv[2], lv[3]);
        }
    };

    f32x4 acc[2][4];
    #pragma unroll
    for (int i = 0; i < 2; ++i)
        #pragma unroll
        for (int n = 0; n < 4; ++n)
            acc[i][n] = f32x4{0.f, 0.f, 0.f, 0.f};

    // prologue stage of tile0/chunk0 into buffer 0
    load_w(vbase, 0);
    store_w(&w_hi_s[0][0], &w_lo_s[0][0]);
    __syncthreads();

    for (int tt = 0; tt < NT; ++tt) {
        const int v0 = vbase + tt * BN;
        #pragma unroll
        for (int ck = 0; ck < 4; ++ck) {
            const bool last = (tt == NT - 1) && (ck == 3);

            // issue next chunk's global loads NOW (in flight across compute)
            if (!last) {
                const int nv0 = (ck == 3) ? v0 + BN : v0;
                const int nk0 = (ck == 3) ? 0 : (ck + 1) * BK;
                load_w(nv0, nk0);
            }

            // compute chunk ck from buffer ck&1 (A from registers)
            {
                const unsigned short* whc = &w_hi_s[ck & 1][0];
                const unsigned short* wlc = &w_lo_s[ck & 1][0];
                #pragma unroll
                for (int ks = 0; ks < 2; ++ks) {
                    const int kb = ks * 64 + (lane >> 4) * 16;
                    bf16x8 bh[4], bl[4];
                    #pragma unroll
                    for (int n = 0; n < 4; ++n) {
                        const int row = wn * 64 + n * 16 + (lane & 15);
                        const int off = row * (BK * 2) + (kb ^ ((row & 7) << 4));
                        bh[n] = *reinterpret_cast<const bf16x8*>(
                                    reinterpret_cast<const char*>(whc) + off);
                        bl[n] = *reinterpret_cast<const bf16x8*>(
                                    reinterpret_cast<const char*>(wlc) + off);
                    }
                    #pragma unroll
                    for (int n = 0; n < 4; ++n)
                        #pragma unroll
                        for (int i = 0; i < 2; ++i) {
                            const bf16x8 a_h = aH[ck * 4 + i * 2 + ks];
                            const bf16x8 a_l = aL[ck * 4 + i * 2 + ks];
                            acc[i][n] = __builtin_amdgcn_mfma_f32_16x16x32_bf16(a_h, bh[n], acc[i][n], 0, 0, 0);
                            acc[i][n] = __builtin_amdgcn_mfma_f32_16x16x32_bf16(a_h, bl[n], acc[i][n], 0, 0, 0);
                            acc[i][n] = __builtin_amdgcn_mfma_f32_16x16x32_bf16(a_l, bh[n], acc[i][n], 0, 0, 0);
                        }
                }
            }

            // convert + publish next buffer (waits wreg vmcnt; loads had the
            // whole compute phase in flight)
            if (!last)
                store_w(&w_hi_s[(ck + 1) & 1][0], &w_lo_s[(ck + 1) & 1][0]);

            // end of tile: bias + tanh + masked store, reset acc
            if (ck == 3) {
                float bias[4];
                int   cols[4];
                #pragma unroll
                for (int n = 0; n < 4; ++n) {
                    const int c = v0 + wn * 64 + n * 16 + (lane & 15);
                    cols[n] = c;
                    bias[n] = (c < V) ? b_out[c] : 0.f;
                }
                const int rbase = b0 + wm * 32 + (lane >> 4) * 4;
                #pragma unroll
                for (int i = 0; i < 2; ++i)
                    #pragma unroll
                    for (int r = 0; r < 4; ++r) {
                        const int row = rbase + i * 16 + r;
                        float* dst = logit + (size_t)row * V;
                        #pragma unroll
                        for (int n = 0; n < 4; ++n) {
                            if (cols[n] < V)
                                dst[cols[n]] = fast_tanh(acc[i][n][r] + bias[n]);
                        }
                    }
                #pragma unroll
                for (int i = 0; i < 2; ++i)
                    #pragma unroll
                    for (int n = 0; n < 4; ++n)
                        acc[i][n] = f32x4{0.f, 0.f, 0.f, 0.f};
            }

            __syncthreads();   // one barrier per chunk
        }
    }
}

// ---------------------------------------------------------------------------
// Fallback kernel (round-4, proven): reg-staged split-bf16 GEMM, used only if
// ws_size can't hold the h planes. Needs no workspace.
// ---------------------------------------------------------------------------
#define NVB 782   // ceil(V/BN)
#define NBB 8     // B/BM

__global__ __launch_bounds__(256) void out_gemm_mfma_reg(
    const float* __restrict__ hnew,
    const float* __restrict__ w_out,
    const float* __restrict__ b_out,
    float*       __restrict__ logit)
{
    __shared__ unsigned short w_hi[BN * BK];
    __shared__ unsigned short w_lo[BN * BK];
    __shared__ unsigned short h_hi[BM * BK];
    __shared__ unsigned short h_lo[BM * BK];

    const int tid  = threadIdx.x;
    const int lane = tid & 63;
    const int wid  = tid >> 6;
    const int wm   = wid >> 1;
    const int wn   = wid & 1;

    const int bid = blockIdx.x;
    const int wg  = (bid & 7) * NVB + (bid >> 3);
    const int bx  = wg & 7;
    const int by  = wg >> 3;
    const int b0  = bx * BM;
    const int v0  = by * BN;

    float4 wreg[8];
    float4 hreg[4];

    auto load_chunk = [&](int k0) {
        #pragma unroll
        for (int i = 0; i < 8; ++i) {
            const int idx4 = i * 256 + tid;
            const int row  = idx4 >> 4;
            const int k4   = (idx4 & 15) << 2;
            int vgl = v0 + row; if (vgl > V - 1) vgl = V - 1;
            wreg[i] = *reinterpret_cast<const float4*>(&w_out[(size_t)vgl * H + k0 + k4]);
        }
        #pragma unroll
        for (int i = 0; i < 4; ++i) {
            const int idx4 = i * 256 + tid;
            const int row  = idx4 >> 4;
            const int k4   = (idx4 & 15) << 2;
            hreg[i] = *reinterpret_cast<const float4*>(&hnew[(b0 + row) * H + k0 + k4]);
        }
    };

    auto store_chunk = [&]() {
        #pragma unroll
        for (int i = 0; i < 8; ++i) {
            const int idx4 = i * 256 + tid;
            const int row  = idx4 >> 4;
            const int k4   = (idx4 & 15) << 2;
            const int off  = row * (BK * 2) + ((k4 * 2) ^ ((row & 7) << 4));
            const float f[4] = {wreg[i].x, wreg[i].y, wreg[i].z, wreg[i].w};
            unsigned short hv[4], lv[4];
            #pragma unroll
            for (int jj = 0; jj < 4; ++jj) {
                hv[jj] = f32_bf16_rne(f[jj]);
                lv[jj] = f32_bf16_rne(f[jj] - bf16u_f32(hv[jj]));
            }
            *reinterpret_cast<ushort4*>(reinterpret_cast<char*>(w_hi) + off) =
                make_ushort4(hv[0], hv[1], hv[2], hv[3]);
            *reinterpret_cast<ushort4*>(reinterpret_cast<char*>(w_lo) + off) =
                make_ushort4(lv[0], lv[1], lv[2], lv[3]);
        }
        #pragma unroll
        for (int i = 0; i < 4; ++i) {
            const int idx4 = i * 256 + tid;
            const int row  = idx4 >> 4;
            const int k4   = (idx4 & 15) << 2;
            const int off  = row * (BK * 2) + ((k4 * 2) ^ ((row & 7) << 4));
            const float f[4] = {hreg[i].x, hreg[i].y, hreg[i].z, hreg[i].w};
            unsigned short hv[4], lv[4];
            #pragma unroll
            for (int jj = 0; jj < 4; ++jj) {
                hv[jj] = f32_bf16_rne(f[jj]);
                lv[jj] = f32_bf16_rne(f[jj] - bf16u_f32(hv[jj]));
            }
            *reinterpret_cast<ushort4*>(reinterpret_cast<char*>(h_hi) + off) =
                make_ushort4(hv[0], hv[1], hv[2], hv[3]);
            *reinterpret_cast<ushort4*>(reinterpret_cast<char*>(h_lo) + off) =
                make_ushort4(lv[0], lv[1], lv[2], lv[3]);
        }
    };

    f32x4 acc[2][4];
    #pragma unroll
    for (int i = 0; i < 2; ++i)
        #pragma unroll
        for (int n = 0; n < 4; ++n)
            acc[i][n] = f32x4{0.f, 0.f, 0.f, 0.f};

    auto compute = [&]() {
        #pragma unroll
        for (int ks = 0; ks < 2; ++ks) {
            const int kb = ks * 64 + (lane >> 4) * 16;
            bf16x8 ah[2], al[2];
            #pragma unroll
            for (int i = 0; i < 2; ++i) {
                const int row = wm * 32 + i * 16 + (lane & 15);
                const int off = row * (BK * 2) + (kb ^ ((row & 7) << 4));
                ah[i] = *reinterpret_cast<const bf16x8*>(
                            reinterpret_cast<const char*>(h_hi) + off);
                al[i] = *reinterpret_cast<const bf16x8*>(
                            reinterpret_cast<const char*>(h_lo) + off);
            }
            #pragma unroll
            for (int n = 0; n < 4; ++n) {
                const int row = wn * 64 + n * 16 + (lane & 15);
                const int off = row * (BK * 2) + (kb ^ ((row & 7) << 4));
                const bf16x8 bh = *reinterpret_cast<const bf16x8*>(
                            reinterpret_cast<const char*>(w_hi) + off);
                const bf16x8 bl = *reinterpret_cast<const bf16x8*>(
                            reinterpret_cast<const char*>(w_lo) + off);
                #pragma unroll
                for (int i = 0; i < 2; ++i) {
                    acc[i][n] = __builtin_amdgcn_mfma_f32_16x16x32_bf16(ah[i], bh, acc[i][n], 0, 0, 0);
                    acc[i][n] = __builtin_amdgcn_mfma_f32_16x16x32_bf16(ah[i], bl, acc[i][n], 0, 0, 0);
                    acc[i][n] = __builtin_amdgcn_mfma_f32_16x16x32_bf16(al[i], bh, acc[i][n], 0, 0, 0);
                }
            }
        }
    };

    load_chunk(0);
    store_chunk();
    __syncthreads();
    for (int t = 0; t < 4; ++t) {
        if (t < 3) load_chunk((t + 1) * BK);
        compute();
        __syncthreads();
        if (t < 3) { store_chunk(); __syncthreads(); }
    }

    float bias[4];
    int   cols[4];
    #pragma unroll
    for (int n = 0; n < 4; ++n) {
        const int c = v0 + wn * 64 + n * 16 + (lane & 15);
        cols[n] = c;
        bias[n] = (c < V) ? b_out[c] : 0.f;
    }
    const int rbase = b0 + wm * 32 + (lane >> 4) * 4;
    #pragma unroll
    for (int i = 0; i < 2; ++i) {
        #pragma unroll
        for (int r = 0; r < 4; ++r) {
            const int row = rbase + i * 16 + r;
            float* dst = logit + (size_t)row * V;
            #pragma unroll
            for (int n = 0; n < 4; ++n) {
                if (cols[n] < V)
                    dst[cols[n]] = tanhf(acc[i][n][r] + bias[n]);
            }
        }
    }
}

// ---------------------------------------------------------------------------
extern "C" void kernel_launch(void* const* d_in, const int* in_sizes, int n_in,
                              void* d_out, int out_size, void* d_ws, size_t ws_size,
                              hipStream_t stream) {
    const int*   input  = (const int*)  d_in[0];
    // d_in[1] = target (unused by forward)
    const float* hidden = (const float*)d_in[2];
    const float* w_ih   = (const float*)d_in[3];
    const float* w_hh   = (const float*)d_in[4];
    const float* b_ih   = (const float*)d_in[5];
    const float* b_hh   = (const float*)d_in[6];
    const float* w_out  = (const float*)d_in[7];
    const float* b_out  = (const float*)d_in[8];

    float* out   = (float*)d_out;
    float* logit = out;                      // first B*V floats
    float* h_new = out + (size_t)B * V;      // then L*B*H floats (L=1)

    const size_t nh = (size_t)B * H;                          // 131,072
    const size_t needed = 2 * nh * sizeof(unsigned short);    // 512 KB

    if (ws_size >= needed) {
        unsigned short* hhi = (unsigned short*)d_ws;
        unsigned short* hlo = hhi + nh;

        gru_cell_v3<<<256, 256, 0, stream>>>(input, hidden, w_ih, w_hh,
                                             b_ih, b_hh, h_new, hhi, hlo);
        out_gemm_tiles<<<GRID2, 256, 0, stream>>>(w_out, hhi, hlo,
                                                  b_out, logit);
    } else {
        gru_cell_v3<<<256, 256, 0, stream>>>(input, hidden, w_ih, w_hh,
                                             b_ih, b_hh, h_new,
                                             nullptr, nullptr);
        out_gemm_mfma_reg<<<NVB * NBB, 256, 0, stream>>>(h_new, w_out,
                                                         b_out, logit);
    }
}

// Round 12
// 269.363 us; speedup vs baseline: 1.4168x; 1.4168x over previous
//
#include <hip/hip_runtime.h>
#include <hip/hip_bf16.h>
#include <math.h>

#define V 100000
#define H 256
#define B 512

typedef __bf16 bf16x8 __attribute__((ext_vector_type(8)));
typedef float  f32x4  __attribute__((ext_vector_type(4)));

__device__ __forceinline__ unsigned short f32_bf16_rne(float x) {
    unsigned u = __float_as_uint(x);
    u += 0x7FFFu + ((u >> 16) & 1u);            // round-to-nearest-even
    return (unsigned short)(u >> 16);
}
__device__ __forceinline__ float bf16u_f32(unsigned short h) {
    return __uint_as_float(((unsigned)h) << 16);
}
__device__ __forceinline__ float fast_tanh(float x) {
    float e = __builtin_exp2f(x * 2.8853900817779268f);
    return 1.f - 2.f * __builtin_amdgcn_rcpf(e + 1.f);
}

#define GLOAD_LDS16(g, l)                                                     \
    __builtin_amdgcn_global_load_lds(                                         \
        (const __attribute__((address_space(1))) void*)(g),                   \
        (__attribute__((address_space(3))) void*)(l), 16, 0, 0)

#define WAIT_VM(N) asm volatile("s_waitcnt vmcnt(" #N ")" ::: "memory")
#define SCHED_FENCE() __builtin_amdgcn_sched_barrier(0)

// ---------------------------------------------------------------------------
// Kernel 1 (fused, verbatim R10-proven): blocks 0..255 = GRU cell v3;
// blocks 256..2303 = split w_out fp32 -> bf16 hi/lo planes.
// ---------------------------------------------------------------------------
#define PREP_GRID 2304

__global__ __launch_bounds__(256) void gru_and_split(
    const int*   __restrict__ input,
    const float* __restrict__ hidden,
    const float* __restrict__ w_ih,
    const float* __restrict__ w_hh,
    const float* __restrict__ b_ih,
    const float* __restrict__ b_hh,
    const float* __restrict__ w_out,
    float*       __restrict__ h_out,
    unsigned short* __restrict__ h_hi_p,
    unsigned short* __restrict__ h_lo_p,
    unsigned short* __restrict__ w_hi_p,
    unsigned short* __restrict__ w_lo_p)
{
    if (blockIdx.x >= 256) {
        const int total4 = (V * H) / 4;
        for (int i = (blockIdx.x - 256) * 256 + threadIdx.x; i < total4;
             i += 2048 * 256) {
            const float4 x = reinterpret_cast<const float4*>(w_out)[i];
            const float f[4] = {x.x, x.y, x.z, x.w};
            ushort4 hv, lv;
            unsigned short* hp = &hv.x;
            unsigned short* lp = &lv.x;
            #pragma unroll
            for (int jj = 0; jj < 4; ++jj) {
                hp[jj] = f32_bf16_rne(f[jj]);
                lp[jj] = f32_bf16_rne(f[jj] - bf16u_f32(hp[jj]));
            }
            reinterpret_cast<ushort4*>(w_hi_p)[i] = hv;
            reinterpret_cast<ushort4*>(w_lo_p)[i] = lv;
        }
        return;
    }

    const int gb  = blockIdx.x >> 2;
    const int q   = blockIdx.x & 3;
    const int b0  = gb * 8;
    const int j0  = q * 64;
    const int tid = threadIdx.x;
    const int jj  = tid & 63;
    const int bq  = tid >> 6;
    const int j   = j0 + jj;

    __shared__ float hs[8 * H];
    __shared__ int   idxs[8];
    #pragma unroll
    for (int i = 0; i < 2; ++i) {
        const int p = i * 256 + tid;
        reinterpret_cast<float4*>(hs)[p] =
            reinterpret_cast<const float4*>(hidden + (size_t)b0 * H)[p];
    }
    if (tid < 8) idxs[tid] = input[b0 + tid];
    __syncthreads();

    const int ba = bq * 2, bb = bq * 2 + 1;
    const int ia = idxs[ba], ib = idxs[bb];

    const float g_ra = w_ih[(size_t) j          * V + ia];
    const float g_rb = w_ih[(size_t) j          * V + ib];
    const float g_za = w_ih[(size_t)(j +     H) * V + ia];
    const float g_zb = w_ih[(size_t)(j +     H) * V + ib];
    const float g_na = w_ih[(size_t)(j + 2 * H) * V + ia];
    const float g_nb = w_ih[(size_t)(j + 2 * H) * V + ib];

    const float4* wr = reinterpret_cast<const float4*>(&w_hh[(size_t) j          * H]);
    const float4* wz = reinterpret_cast<const float4*>(&w_hh[(size_t)(j +     H) * H]);
    const float4* wn = reinterpret_cast<const float4*>(&w_hh[(size_t)(j + 2 * H) * H]);
    const float4* ha = reinterpret_cast<const float4*>(&hs[ba * H]);
    const float4* hb = reinterpret_cast<const float4*>(&hs[bb * H]);

    float ara = 0.f, aza = 0.f, ana = 0.f;
    float arb = 0.f, azb = 0.f, anb = 0.f;
    #pragma unroll 4
    for (int k = 0; k < H / 4; ++k) {
        const float4 a = wr[k];
        const float4 c = wz[k];
        const float4 d = wn[k];
        const float4 va = ha[k];
        const float4 vb = hb[k];
        ara += a.x * va.x + a.y * va.y + a.z * va.z + a.w * va.w;
        aza += c.x * va.x + c.y * va.y + c.z * va.z + c.w * va.w;
        ana += d.x * va.x + d.y * va.y + d.z * va.z + d.w * va.w;
        arb += a.x * vb.x + a.y * vb.y + a.z * vb.z + a.w * vb.w;
        azb += c.x * vb.x + c.y * vb.y + c.z * vb.z + c.w * vb.w;
        anb += d.x * vb.x + d.y * vb.y + d.z * vb.z + d.w * vb.w;
    }

    const float bir = b_ih[j], biz = b_ih[j + H], bin = b_ih[j + 2 * H];
    const float bhr = b_hh[j], bhz = b_hh[j + H], bhn = b_hh[j + 2 * H];

    #pragma unroll
    for (int s = 0; s < 2; ++s) {
        const float gi_r = (s ? g_rb : g_ra) + bir;
        const float gi_z = (s ? g_zb : g_za) + biz;
        const float gi_n = (s ? g_nb : g_na) + bin;
        const float h_r  = (s ? arb : ara) + bhr;
        const float h_z  = (s ? azb : aza) + bhz;
        const float h_n  = (s ? anb : ana) + bhn;
        const int   bg   = b0 + (s ? bb : ba);

        const float r = 1.f / (1.f + expf(-(gi_r + h_r)));
        const float z = 1.f / (1.f + expf(-(gi_z + h_z)));
        const float n = tanhf(gi_n + r * h_n);
        const float hprev = hs[(s ? bb : ba) * H + jj + j0];
        const float val = (1.f - z) * n + z * hprev;

        h_out[(size_t)bg * H + j] = val;
        if (h_hi_p != nullptr) {
            const unsigned short hh = f32_bf16_rne(val);
            h_hi_p[(size_t)bg * H + j] = hh;
            h_lo_p[(size_t)bg * H + j] = f32_bf16_rne(val - bf16u_f32(hh));
        }
    }
}

// ---------------------------------------------------------------------------
// Kernel 2 (T4 counted-vmcnt): logit = tanh(h_new @ w_out.T + b_out).
// R6's proven staging/fragment/swizzle math, but:
//  - DOUBLE-buffered w LDS (2 x 32 KB) staged via global_load_lds;
//  - raw s_barrier + s_waitcnt vmcnt(8): next chunk's 8 loads stay IN FLIGHT
//    across the barrier and the whole compute phase (never drain to 0 in
//    steady state) -- the T4 lever all prior rounds lacked;
//  - wave tile 16 batch x 128 vocab: A-frags for ALL K in 64 VGPR, loaded
//    once in the prologue and drained there (keeps manual vmcnt counts exact);
//  - sched_barrier(0) after every asm wait (rule 18), setprio around MFMA.
// ---------------------------------------------------------------------------
#define BM  64
#define BN  128
#define BK  64
#define NVB 782   // ceil(V/BN); 8*782 = 6256 grid, bijective XCD swizzle
#define NBB 8     // B/BM

__global__ __launch_bounds__(256, 2) void out_gemm_cnt(
    const unsigned short* __restrict__ whi_g,  // (V,H) bf16 hi plane
    const unsigned short* __restrict__ wlo_g,  // (V,H) bf16 lo plane
    const unsigned short* __restrict__ hhi_g,  // (B,H) bf16 hi plane
    const unsigned short* __restrict__ hlo_g,  // (B,H) bf16 lo plane
    const float*          __restrict__ b_out,  // (V)
    float*                __restrict__ logit)  // (B,V)
{
    __shared__ unsigned short w_hi_s[2][BN * BK];   // 2 x 16 KB
    __shared__ unsigned short w_lo_s[2][BN * BK];   // 2 x 16 KB

    const int tid  = threadIdx.x;
    const int lane = tid & 63;
    const int wid  = tid >> 6;          // wave 0..3 -> 16-row batch slice

    const int bid = blockIdx.x;                    // 0..6255
    const int wg  = (bid & 7) * NVB + (bid >> 3);
    const int bx  = wg & 7;                        // batch block
    const int by  = wg >> 3;                       // vocab block
    const int b0  = bx * BM;
    const int v0  = by * BN;

    // ---- prologue: A-fragments for all K=256 into 64 VGPR, drained now ----
    bf16x8 aH[8], aL[8];                // kstep s = 0..7
    {
        const int arow = b0 + wid * 16 + (lane & 15);
        #pragma unroll
        for (int s = 0; s < 8; ++s) {
            const size_t ho = ((size_t)arow * H + s * 32 + (lane >> 4) * 8) * 2;
            aH[s] = *reinterpret_cast<const bf16x8*>(
                        reinterpret_cast<const char*>(hhi_g) + ho);
            aL[s] = *reinterpret_cast<const bf16x8*>(
                        reinterpret_cast<const char*>(hlo_g) + ho);
        }
    }
    WAIT_VM(0);          // drain A-loads so loop vmcnt counting is exact
    SCHED_FENCE();

    // ---- staging: 8 global_load_lds per wave per chunk (R6 addressing) ----
    auto stage = [&](int buf, int k0) {
        #pragma unroll
        for (int i = 0; i < 4; ++i) {
            const int p    = i * 4096 + (wid << 10) + (lane << 4);
            const int row  = p >> 7;               // local vocab row 0..127
            const int lb   = p & 127;
            const int swz  = lb ^ ((row & 7) << 4);
            int vg = v0 + row; if (vg > V - 1) vg = V - 1;
            const size_t gb = (size_t)vg * (H * 2) + (size_t)(k0 * 2) + swz;
            const int dst  = i * 4096 + (wid << 10);
            GLOAD_LDS16((const char*)whi_g + gb,
                        (char*)&w_hi_s[buf][0] + dst);
            GLOAD_LDS16((const char*)wlo_g + gb,
                        (char*)&w_lo_s[buf][0] + dst);
        }
    };

    f32x4 acc[8];
    #pragma unroll
    for (int n = 0; n < 8; ++n) acc[n] = f32x4{0.f, 0.f, 0.f, 0.f};

    auto compute = [&](int buf, int t) {
        __builtin_amdgcn_s_setprio(1);
        #pragma unroll
        for (int ks = 0; ks < 2; ++ks) {
            const int s  = t * 2 + ks;
            const int kb = ks * 64 + (lane >> 4) * 16;
            const bf16x8 a_h = aH[s];
            const bf16x8 a_l = aL[s];
            #pragma unroll
            for (int n = 0; n < 8; ++n) {
                const int row = n * 16 + (lane & 15);
                const int off = row * (BK * 2) + (kb ^ ((row & 7) << 4));
                const bf16x8 bh = *reinterpret_cast<const bf16x8*>(
                            reinterpret_cast<const char*>(&w_hi_s[buf][0]) + off);
                const bf16x8 bl = *reinterpret_cast<const bf16x8*>(
                            reinterpret_cast<const char*>(&w_lo_s[buf][0]) + off);
                acc[n] = __builtin_amdgcn_mfma_f32_16x16x32_bf16(a_h, bh, acc[n], 0, 0, 0);
                acc[n] = __builtin_amdgcn_mfma_f32_16x16x32_bf16(a_h, bl, acc[n], 0, 0, 0);
                acc[n] = __builtin_amdgcn_mfma_f32_16x16x32_bf16(a_l, bh, acc[n], 0, 0, 0);
            }
        }
        __builtin_amdgcn_s_setprio(0);
    };

    // ---- counted-vmcnt pipeline: K = 4 chunks of 64, dbuf, never drain ----
    stage(0, 0);                 //  8 in flight
    stage(1, 64);                // 16 in flight
    WAIT_VM(8);                  // buf0's 8 done; buf1's 8 stay in flight
    __builtin_amdgcn_s_barrier();
    SCHED_FENCE();

    compute(0, 0);               // buf1 loads land under this
    SCHED_FENCE();
    __builtin_amdgcn_s_barrier();    // all waves done reading buf0
    stage(0, 128);               // in flight: buf1(8) + buf0'(8)
    WAIT_VM(8);                  // buf1 ready; buf0' stays in flight
    __builtin_amdgcn_s_barrier();
    SCHED_FENCE();

    compute(1, 1);
    SCHED_FENCE();
    __builtin_amdgcn_s_barrier();
    stage(1, 192);
    WAIT_VM(8);
    __builtin_amdgcn_s_barrier();
    SCHED_FENCE();

    compute(0, 2);
    SCHED_FENCE();
    WAIT_VM(0);                  // buf1@192 (had full compute in flight)
    __builtin_amdgcn_s_barrier();
    SCHED_FENCE();

    compute(1, 3);

    // ---- epilogue: bias + tanh + masked store (proven mapping) ----
    float bias[8];
    int   cols[8];
    #pragma unroll
    for (int n = 0; n < 8; ++n) {
        const int c = v0 + n * 16 + (lane & 15);
        cols[n] = c;
        bias[n] = (c < V) ? b_out[c] : 0.f;
    }
    const int rbase = b0 + wid * 16 + (lane >> 4) * 4;
    #pragma unroll
    for (int r = 0; r < 4; ++r) {
        const int row = rbase + r;
        float* dst = logit + (size_t)row * V;
        #pragma unroll
        for (int n = 0; n < 8; ++n) {
            if (cols[n] < V)
                dst[cols[n]] = fast_tanh(acc[n][r] + bias[n]);
        }
    }
}

// ---------------------------------------------------------------------------
// Fallback kernel (round-4, proven): reg-staged split-bf16 GEMM, no workspace.
// ---------------------------------------------------------------------------
__global__ __launch_bounds__(256) void out_gemm_mfma_reg(
    const float* __restrict__ hnew,
    const float* __restrict__ w_out,
    const float* __restrict__ b_out,
    float*       __restrict__ logit)
{
    __shared__ unsigned short w_hi[BN * BK];
    __shared__ unsigned short w_lo[BN * BK];
    __shared__ unsigned short h_hi[BM * BK];
    __shared__ unsigned short h_lo[BM * BK];

    const int tid  = threadIdx.x;
    const int lane = tid & 63;
    const int wid  = tid >> 6;
    const int wm   = wid >> 1;
    const int wn   = wid & 1;

    const int bid = blockIdx.x;
    const int wg  = (bid & 7) * NVB + (bid >> 3);
    const int bx  = wg & 7;
    const int by  = wg >> 3;
    const int b0  = bx * BM;
    const int v0  = by * BN;

    float4 wreg[8];
    float4 hreg[4];

    auto load_chunk = [&](int k0) {
        #pragma unroll
        for (int i = 0; i < 8; ++i) {
            const int idx4 = i * 256 + tid;
            const int row  = idx4 >> 4;
            const int k4   = (idx4 & 15) << 2;
            int vgl = v0 + row; if (vgl > V - 1) vgl = V - 1;
            wreg[i] = *reinterpret_cast<const float4*>(&w_out[(size_t)vgl * H + k0 + k4]);
        }
        #pragma unroll
        for (int i = 0; i < 4; ++i) {
            const int idx4 = i * 256 + tid;
            const int row  = idx4 >> 4;
            const int k4   = (idx4 & 15) << 2;
            hreg[i] = *reinterpret_cast<const float4*>(&hnew[(b0 + row) * H + k0 + k4]);
        }
    };

    auto store_chunk = [&]() {
        #pragma unroll
        for (int i = 0; i < 8; ++i) {
            const int idx4 = i * 256 + tid;
            const int row  = idx4 >> 4;
            const int k4   = (idx4 & 15) << 2;
            const int off  = row * (BK * 2) + ((k4 * 2) ^ ((row & 7) << 4));
            const float f[4] = {wreg[i].x, wreg[i].y, wreg[i].z, wreg[i].w};
            unsigned short hv[4], lv[4];
            #pragma unroll
            for (int jj = 0; jj < 4; ++jj) {
                hv[jj] = f32_bf16_rne(f[jj]);
                lv[jj] = f32_bf16_rne(f[jj] - bf16u_f32(hv[jj]));
            }
            *reinterpret_cast<ushort4*>(reinterpret_cast<char*>(w_hi) + off) =
                make_ushort4(hv[0], hv[1], hv[2], hv[3]);
            *reinterpret_cast<ushort4*>(reinterpret_cast<char*>(w_lo) + off) =
                make_ushort4(lv[0], lv[1], lv[2], lv[3]);
        }
        #pragma unroll
        for (int i = 0; i < 4; ++i) {
            const int idx4 = i * 256 + tid;
            const int row  = idx4 >> 4;
            const int k4   = (idx4 & 15) << 2;
            const int off  = row * (BK * 2) + ((k4 * 2) ^ ((row & 7) << 4));
            const float f[4] = {hreg[i].x, hreg[i].y, hreg[i].z, hreg[i].w};
            unsigned short hv[4], lv[4];
            #pragma unroll
            for (int jj = 0; jj < 4; ++jj) {
                hv[jj] = f32_bf16_rne(f[jj]);
                lv[jj] = f32_bf16_rne(f[jj] - bf16u_f32(hv[jj]));
            }
            *reinterpret_cast<ushort4*>(reinterpret_cast<char*>(h_hi) + off) =
                make_ushort4(hv[0], hv[1], hv[2], hv[3]);
            *reinterpret_cast<ushort4*>(reinterpret_cast<char*>(h_lo) + off) =
                make_ushort4(lv[0], lv[1], lv[2], lv[3]);
        }
    };

    f32x4 acc[2][4];
    #pragma unroll
    for (int i = 0; i < 2; ++i)
        #pragma unroll
        for (int n = 0; n < 4; ++n)
            acc[i][n] = f32x4{0.f, 0.f, 0.f, 0.f};

    auto compute = [&]() {
        #pragma unroll
        for (int ks = 0; ks < 2; ++ks) {
            const int kb = ks * 64 + (lane >> 4) * 16;
            bf16x8 ah[2], al[2];
            #pragma unroll
            for (int i = 0; i < 2; ++i) {
                const int row = wm * 32 + i * 16 + (lane & 15);
                const int off = row * (BK * 2) + (kb ^ ((row & 7) << 4));
                ah[i] = *reinterpret_cast<const bf16x8*>(
                            reinterpret_cast<const char*>(h_hi) + off);
                al[i] = *reinterpret_cast<const bf16x8*>(
                            reinterpret_cast<const char*>(h_lo) + off);
            }
            #pragma unroll
            for (int n = 0; n < 4; ++n) {
                const int row = wn * 64 + n * 16 + (lane & 15);
                const int off = row * (BK * 2) + (kb ^ ((row & 7) << 4));
                const bf16x8 bh = *reinterpret_cast<const bf16x8*>(
                            reinterpret_cast<const char*>(w_hi) + off);
                const bf16x8 bl = *reinterpret_cast<const bf16x8*>(
                            reinterpret_cast<const char*>(w_lo) + off);
                #pragma unroll
                for (int i = 0; i < 2; ++i) {
                    acc[i][n] = __builtin_amdgcn_mfma_f32_16x16x32_bf16(ah[i], bh, acc[i][n], 0, 0, 0);
                    acc[i][n] = __builtin_amdgcn_mfma_f32_16x16x32_bf16(ah[i], bl, acc[i][n], 0, 0, 0);
                    acc[i][n] = __builtin_amdgcn_mfma_f32_16x16x32_bf16(al[i], bh, acc[i][n], 0, 0, 0);
                }
            }
        }
    };

    load_chunk(0);
    store_chunk();
    __syncthreads();
    for (int t = 0; t < 4; ++t) {
        if (t < 3) load_chunk((t + 1) * BK);
        compute();
        __syncthreads();
        if (t < 3) { store_chunk(); __syncthreads(); }
    }

    float bias[4];
    int   cols[4];
    #pragma unroll
    for (int n = 0; n < 4; ++n) {
        const int c = v0 + wn * 64 + n * 16 + (lane & 15);
        cols[n] = c;
        bias[n] = (c < V) ? b_out[c] : 0.f;
    }
    const int rbase = b0 + wm * 32 + (lane >> 4) * 4;
    #pragma unroll
    for (int i = 0; i < 2; ++i) {
        #pragma unroll
        for (int r = 0; r < 4; ++r) {
            const int row = rbase + i * 16 + r;
            float* dst = logit + (size_t)row * V;
            #pragma unroll
            for (int n = 0; n < 4; ++n) {
                if (cols[n] < V)
                    dst[cols[n]] = tanhf(acc[i][n][r] + bias[n]);
            }
        }
    }
}

// ---------------------------------------------------------------------------
extern "C" void kernel_launch(void* const* d_in, const int* in_sizes, int n_in,
                              void* d_out, int out_size, void* d_ws, size_t ws_size,
                              hipStream_t stream) {
    const int*   input  = (const int*)  d_in[0];
    // d_in[1] = target (unused by forward)
    const float* hidden = (const float*)d_in[2];
    const float* w_ih   = (const float*)d_in[3];
    const float* w_hh   = (const float*)d_in[4];
    const float* b_ih   = (const float*)d_in[5];
    const float* b_hh   = (const float*)d_in[6];
    const float* w_out  = (const float*)d_in[7];
    const float* b_out  = (const float*)d_in[8];

    float* out   = (float*)d_out;
    float* logit = out;                      // first B*V floats
    float* h_new = out + (size_t)B * V;      // then L*B*H floats (L=1)

    const size_t nw = (size_t)V * H;         // 25,600,000
    const size_t nh = (size_t)B * H;         // 131,072
    const size_t needed = (2 * nw + 2 * nh) * sizeof(unsigned short); // ~103 MB

    if (ws_size >= needed) {
        unsigned short* whi = (unsigned short*)d_ws;
        unsigned short* wlo = whi + nw;
        unsigned short* hhi = wlo + nw;
        unsigned short* hlo = hhi + nh;

        gru_and_split<<<PREP_GRID, 256, 0, stream>>>(
            input, hidden, w_ih, w_hh, b_ih, b_hh, w_out,
            h_new, hhi, hlo, whi, wlo);
        out_gemm_cnt<<<NVB * NBB, 256, 0, stream>>>(whi, wlo, hhi, hlo,
                                                    b_out, logit);
    } else {
        gru_and_split<<<256, 256, 0, stream>>>(
            input, hidden, w_ih, w_hh, b_ih, b_hh, w_out,
            h_new, nullptr, nullptr, nullptr, nullptr);
        out_gemm_mfma_reg<<<NVB * NBB, 256, 0, stream>>>(h_new, w_out,
                                                         b_out, logit);
    }
}

// Round 13
// 237.631 us; speedup vs baseline: 1.6060x; 1.1335x over previous
//
#include <hip/hip_runtime.h>
#include <hip/hip_bf16.h>
#include <math.h>

#define V 100000
#define H 256
#define B 512

typedef __bf16 bf16x8 __attribute__((ext_vector_type(8)));
typedef float  f32x4  __attribute__((ext_vector_type(4)));

__device__ __forceinline__ unsigned short f32_bf16_rne(float x) {
    unsigned u = __float_as_uint(x);
    u += 0x7FFFu + ((u >> 16) & 1u);            // round-to-nearest-even
    return (unsigned short)(u >> 16);
}
__device__ __forceinline__ float bf16u_f32(unsigned short h) {
    return __uint_as_float(((unsigned)h) << 16);
}
__device__ __forceinline__ float fast_tanh(float x) {
    float e = __builtin_exp2f(x * 2.8853900817779268f);
    return 1.f - 2.f * __builtin_amdgcn_rcpf(e + 1.f);
}

// ---------------------------------------------------------------------------
// Kernel 1: GRU cell v3 (proven R9-R12, ~12 us). 256 blocks = 64 batch-groups
// x 4 hidden-quarters. Writes h_new to d_out + B*V and bf16 hi/lo planes of
// h_new to workspace (512 KB).
// ---------------------------------------------------------------------------
__global__ __launch_bounds__(256) void gru_cell_v3(
    const int*   __restrict__ input,
    const float* __restrict__ hidden,
    const float* __restrict__ w_ih,
    const float* __restrict__ w_hh,
    const float* __restrict__ b_ih,
    const float* __restrict__ b_hh,
    float*       __restrict__ h_out,
    unsigned short* __restrict__ h_hi_p,   // may be null (fallback path)
    unsigned short* __restrict__ h_lo_p)
{
    const int gb  = blockIdx.x >> 2;
    const int q   = blockIdx.x & 3;
    const int b0  = gb * 8;
    const int j0  = q * 64;
    const int tid = threadIdx.x;
    const int jj  = tid & 63;
    const int bq  = tid >> 6;
    const int j   = j0 + jj;

    __shared__ float hs[8 * H];
    __shared__ int   idxs[8];
    #pragma unroll
    for (int i = 0; i < 2; ++i) {
        const int p = i * 256 + tid;
        reinterpret_cast<float4*>(hs)[p] =
            reinterpret_cast<const float4*>(hidden + (size_t)b0 * H)[p];
    }
    if (tid < 8) idxs[tid] = input[b0 + tid];
    __syncthreads();

    const int ba = bq * 2, bb = bq * 2 + 1;
    const int ia = idxs[ba], ib = idxs[bb];

    const float g_ra = w_ih[(size_t) j          * V + ia];
    const float g_rb = w_ih[(size_t) j          * V + ib];
    const float g_za = w_ih[(size_t)(j +     H) * V + ia];
    const float g_zb = w_ih[(size_t)(j +     H) * V + ib];
    const float g_na = w_ih[(size_t)(j + 2 * H) * V + ia];
    const float g_nb = w_ih[(size_t)(j + 2 * H) * V + ib];

    const float4* wr = reinterpret_cast<const float4*>(&w_hh[(size_t) j          * H]);
    const float4* wz = reinterpret_cast<const float4*>(&w_hh[(size_t)(j +     H) * H]);
    const float4* wn = reinterpret_cast<const float4*>(&w_hh[(size_t)(j + 2 * H) * H]);
    const float4* ha = reinterpret_cast<const float4*>(&hs[ba * H]);
    const float4* hb = reinterpret_cast<const float4*>(&hs[bb * H]);

    float ara = 0.f, aza = 0.f, ana = 0.f;
    float arb = 0.f, azb = 0.f, anb = 0.f;
    #pragma unroll 4
    for (int k = 0; k < H / 4; ++k) {
        const float4 a = wr[k];
        const float4 c = wz[k];
        const float4 d = wn[k];
        const float4 va = ha[k];
        const float4 vb = hb[k];
        ara += a.x * va.x + a.y * va.y + a.z * va.z + a.w * va.w;
        aza += c.x * va.x + c.y * va.y + c.z * va.z + c.w * va.w;
        ana += d.x * va.x + d.y * va.y + d.z * va.z + d.w * va.w;
        arb += a.x * vb.x + a.y * vb.y + a.z * vb.z + a.w * vb.w;
        azb += c.x * vb.x + c.y * vb.y + c.z * vb.z + c.w * vb.w;
        anb += d.x * vb.x + d.y * vb.y + d.z * vb.z + d.w * vb.w;
    }

    const float bir = b_ih[j], biz = b_ih[j + H], bin = b_ih[j + 2 * H];
    const float bhr = b_hh[j], bhz = b_hh[j + H], bhn = b_hh[j + 2 * H];

    #pragma unroll
    for (int s = 0; s < 2; ++s) {
        const float gi_r = (s ? g_rb : g_ra) + bir;
        const float gi_z = (s ? g_zb : g_za) + biz;
        const float gi_n = (s ? g_nb : g_na) + bin;
        const float h_r  = (s ? arb : ara) + bhr;
        const float h_z  = (s ? azb : aza) + bhz;
        const float h_n  = (s ? anb : ana) + bhn;
        const int   bg   = b0 + (s ? bb : ba);

        const float r = 1.f / (1.f + expf(-(gi_r + h_r)));
        const float z = 1.f / (1.f + expf(-(gi_z + h_z)));
        const float n = tanhf(gi_n + r * h_n);
        const float hprev = hs[(s ? bb : ba) * H + jj + j0];
        const float val = (1.f - z) * n + z * hprev;

        h_out[(size_t)bg * H + j] = val;
        if (h_hi_p != nullptr) {
            const unsigned short hh = f32_bf16_rne(val);
            h_hi_p[(size_t)bg * H + j] = hh;
            h_lo_p[(size_t)bg * H + j] = f32_bf16_rne(val - bf16u_f32(hh));
        }
    }
}

// ---------------------------------------------------------------------------
// Kernel 2 (v13): logit = tanh(h_new @ w_out.T + b_out).
// R4's proven reg-staged two-barrier schedule for w (fp32 read + in-kernel
// hi/lo split -> NO prep kernel), with h removed from LDS entirely:
// A-fragments come from per-lane register loads of the gru-emitted bf16
// planes (addressing proven in R10-lean, passed 2.44e-4). LDS 48->32 KB
// (4 blocks/CU), staging VALU cut by 1/3, fast_tanh epilogue.
// Fragment math / swizzle / XCD mapping byte-identical to R4-R10.
// ---------------------------------------------------------------------------
#define BM  64
#define BN  128
#define BK  64
#define NVB 782   // ceil(V/BN); grid 8*782 = 6256, bijective XCD swizzle
#define NBB 8     // B/BM

__global__ __launch_bounds__(256) void out_gemm_v13(
    const float*          __restrict__ w_out,  // (V,H) fp32
    const unsigned short* __restrict__ hhi_g,  // (B,H) bf16 hi plane
    const unsigned short* __restrict__ hlo_g,  // (B,H) bf16 lo plane
    const float*          __restrict__ b_out,  // (V)
    float*                __restrict__ logit)  // (B,V)
{
    __shared__ unsigned short w_hi_s[BN * BK];   // 16 KB
    __shared__ unsigned short w_lo_s[BN * BK];   // 16 KB

    const int tid  = threadIdx.x;
    const int lane = tid & 63;
    const int wid  = tid >> 6;
    const int wm   = wid >> 1;      // batch half (0..1)
    const int wn   = wid & 1;       // vocab half (0..1)

    const int bid = blockIdx.x;                    // 0..6255
    const int wg  = (bid & 7) * NVB + (bid >> 3);
    const int bx  = wg & 7;                        // batch block
    const int by  = wg >> 3;                       // vocab block
    const int b0  = bx * BM;
    const int v0  = by * BN;

    float4 wreg[8];

    auto load_w = [&](int k0) {
        #pragma unroll
        for (int i = 0; i < 8; ++i) {
            const int u   = i * 256 + tid;
            const int row = u >> 4;            // local vocab row 0..127
            const int k4  = (u & 15) << 2;     // 0..60
            int vg = v0 + row; if (vg > V - 1) vg = V - 1;  // clamp; masked store
            wreg[i] = *reinterpret_cast<const float4*>(&w_out[(size_t)vg * H + k0 + k4]);
        }
    };

    auto store_w = [&]() {
        #pragma unroll
        for (int i = 0; i < 8; ++i) {
            const int u   = i * 256 + tid;
            const int row = u >> 4;
            const int k4  = (u & 15) << 2;
            const int off = row * (BK * 2) + ((k4 * 2) ^ ((row & 7) << 4));
            const float f[4] = {wreg[i].x, wreg[i].y, wreg[i].z, wreg[i].w};
            unsigned short hv[4], lv[4];
            #pragma unroll
            for (int jj = 0; jj < 4; ++jj) {
                hv[jj] = f32_bf16_rne(f[jj]);
                lv[jj] = f32_bf16_rne(f[jj] - bf16u_f32(hv[jj]));
            }
            *reinterpret_cast<ushort4*>(reinterpret_cast<char*>(w_hi_s) + off) =
                make_ushort4(hv[0], hv[1], hv[2], hv[3]);
            *reinterpret_cast<ushort4*>(reinterpret_cast<char*>(w_lo_s) + off) =
                make_ushort4(lv[0], lv[1], lv[2], lv[3]);
        }
    };

    // A fragments from the pre-split h planes (R10-lean proven addressing)
    bf16x8 ah[4], al[4];   // [i*2+ks]
    auto loadA = [&](int t) {
        #pragma unroll
        for (int i = 0; i < 2; ++i) {
            #pragma unroll
            for (int ks = 0; ks < 2; ++ks) {
                const size_t ho = ((size_t)(b0 + wm * 32 + i * 16 + (lane & 15)) * H
                                   + t * BK + ks * 32 + (lane >> 4) * 8) * 2;
                ah[i * 2 + ks] = *reinterpret_cast<const bf16x8*>(
                                     reinterpret_cast<const char*>(hhi_g) + ho);
                al[i * 2 + ks] = *reinterpret_cast<const bf16x8*>(
                                     reinterpret_cast<const char*>(hlo_g) + ho);
            }
        }
    };

    f32x4 acc[2][4];
    #pragma unroll
    for (int i = 0; i < 2; ++i)
        #pragma unroll
        for (int n = 0; n < 4; ++n)
            acc[i][n] = f32x4{0.f, 0.f, 0.f, 0.f};

    auto compute = [&]() {
        #pragma unroll
        for (int ks = 0; ks < 2; ++ks) {
            const int kb = ks * 64 + (lane >> 4) * 16;
            bf16x8 bh[4], bl[4];
            #pragma unroll
            for (int n = 0; n < 4; ++n) {
                const int row = wn * 64 + n * 16 + (lane & 15);
                const int off = row * (BK * 2) + (kb ^ ((row & 7) << 4));
                bh[n] = *reinterpret_cast<const bf16x8*>(
                            reinterpret_cast<const char*>(w_hi_s) + off);
                bl[n] = *reinterpret_cast<const bf16x8*>(
                            reinterpret_cast<const char*>(w_lo_s) + off);
            }
            #pragma unroll
            for (int n = 0; n < 4; ++n) {
                #pragma unroll
                for (int i = 0; i < 2; ++i) {
                    const bf16x8 a_h = ah[i * 2 + ks];
                    const bf16x8 a_l = al[i * 2 + ks];
                    acc[i][n] = __builtin_amdgcn_mfma_f32_16x16x32_bf16(a_h, bh[n], acc[i][n], 0, 0, 0);
                    acc[i][n] = __builtin_amdgcn_mfma_f32_16x16x32_bf16(a_h, bl[n], acc[i][n], 0, 0, 0);
                    acc[i][n] = __builtin_amdgcn_mfma_f32_16x16x32_bf16(a_l, bh[n], acc[i][n], 0, 0, 0);
                }
            }
        }
    };

    // R4's exact two-barrier schedule: convert+publish, barrier, issue next
    // chunk's loads, compute, barrier.
    load_w(0);
    store_w();
    loadA(0);
    __syncthreads();
    #pragma unroll
    for (int t = 0; t < 4; ++t) {
        if (t < 3) load_w((t + 1) * BK);   // next w chunk in flight over compute
        compute();
        __syncthreads();
        if (t < 3) {
            store_w();                      // convert + publish next chunk
            loadA(t + 1);                   // next A frags (drained by barrier)
            __syncthreads();
        }
    }

    // Epilogue: bias + fast_tanh + masked store. C/D: col=lane&15,
    // row=(lane>>4)*4+r (verified r4-r10).
    float bias[4];
    int   cols[4];
    #pragma unroll
    for (int n = 0; n < 4; ++n) {
        const int c = v0 + wn * 64 + n * 16 + (lane & 15);
        cols[n] = c;
        bias[n] = (c < V) ? b_out[c] : 0.f;
    }
    const int rbase = b0 + wm * 32 + (lane >> 4) * 4;
    #pragma unroll
    for (int i = 0; i < 2; ++i) {
        #pragma unroll
        for (int r = 0; r < 4; ++r) {
            const int row = rbase + i * 16 + r;
            float* dst = logit + (size_t)row * V;
            #pragma unroll
            for (int n = 0; n < 4; ++n) {
                if (cols[n] < V)
                    dst[cols[n]] = fast_tanh(acc[i][n][r] + bias[n]);
            }
        }
    }
}

// ---------------------------------------------------------------------------
// Fallback kernel (round-4, proven): reg-staged split-bf16 GEMM, no workspace.
// ---------------------------------------------------------------------------
__global__ __launch_bounds__(256) void out_gemm_mfma_reg(
    const float* __restrict__ hnew,
    const float* __restrict__ w_out,
    const float* __restrict__ b_out,
    float*       __restrict__ logit)
{
    __shared__ unsigned short w_hi[BN * BK];
    __shared__ unsigned short w_lo[BN * BK];
    __shared__ unsigned short h_hi[BM * BK];
    __shared__ unsigned short h_lo[BM * BK];

    const int tid  = threadIdx.x;
    const int lane = tid & 63;
    const int wid  = tid >> 6;
    const int wm   = wid >> 1;
    const int wn   = wid & 1;

    const int bid = blockIdx.x;
    const int wg  = (bid & 7) * NVB + (bid >> 3);
    const int bx  = wg & 7;
    const int by  = wg >> 3;
    const int b0  = bx * BM;
    const int v0  = by * BN;

    float4 wreg[8];
    float4 hreg[4];

    auto load_chunk = [&](int k0) {
        #pragma unroll
        for (int i = 0; i < 8; ++i) {
            const int idx4 = i * 256 + tid;
            const int row  = idx4 >> 4;
            const int k4   = (idx4 & 15) << 2;
            int vgl = v0 + row; if (vgl > V - 1) vgl = V - 1;
            wreg[i] = *reinterpret_cast<const float4*>(&w_out[(size_t)vgl * H + k0 + k4]);
        }
        #pragma unroll
        for (int i = 0; i < 4; ++i) {
            const int idx4 = i * 256 + tid;
            const int row  = idx4 >> 4;
            const int k4   = (idx4 & 15) << 2;
            hreg[i] = *reinterpret_cast<const float4*>(&hnew[(b0 + row) * H + k0 + k4]);
        }
    };

    auto store_chunk = [&]() {
        #pragma unroll
        for (int i = 0; i < 8; ++i) {
            const int idx4 = i * 256 + tid;
            const int row  = idx4 >> 4;
            const int k4   = (idx4 & 15) << 2;
            const int off  = row * (BK * 2) + ((k4 * 2) ^ ((row & 7) << 4));
            const float f[4] = {wreg[i].x, wreg[i].y, wreg[i].z, wreg[i].w};
            unsigned short hv[4], lv[4];
            #pragma unroll
            for (int jj = 0; jj < 4; ++jj) {
                hv[jj] = f32_bf16_rne(f[jj]);
                lv[jj] = f32_bf16_rne(f[jj] - bf16u_f32(hv[jj]));
            }
            *reinterpret_cast<ushort4*>(reinterpret_cast<char*>(w_hi) + off) =
                make_ushort4(hv[0], hv[1], hv[2], hv[3]);
            *reinterpret_cast<ushort4*>(reinterpret_cast<char*>(w_lo) + off) =
                make_ushort4(lv[0], lv[1], lv[2], lv[3]);
        }
        #pragma unroll
        for (int i = 0; i < 4; ++i) {
            const int idx4 = i * 256 + tid;
            const int row  = idx4 >> 4;
            const int k4   = (idx4 & 15) << 2;
            const int off  = row * (BK * 2) + ((k4 * 2) ^ ((row & 7) << 4));
            const float f[4] = {hreg[i].x, hreg[i].y, hreg[i].z, hreg[i].w};
            unsigned short hv[4], lv[4];
            #pragma unroll
            for (int jj = 0; jj < 4; ++jj) {
                hv[jj] = f32_bf16_rne(f[jj]);
                lv[jj] = f32_bf16_rne(f[jj] - bf16u_f32(hv[jj]));
            }
            *reinterpret_cast<ushort4*>(reinterpret_cast<char*>(h_hi) + off) =
                make_ushort4(hv[0], hv[1], hv[2], hv[3]);
            *reinterpret_cast<ushort4*>(reinterpret_cast<char*>(h_lo) + off) =
                make_ushort4(lv[0], lv[1], lv[2], lv[3]);
        }
    };

    f32x4 acc[2][4];
    #pragma unroll
    for (int i = 0; i < 2; ++i)
        #pragma unroll
        for (int n = 0; n < 4; ++n)
            acc[i][n] = f32x4{0.f, 0.f, 0.f, 0.f};

    auto compute = [&]() {
        #pragma unroll
        for (int ks = 0; ks < 2; ++ks) {
            const int kb = ks * 64 + (lane >> 4) * 16;
            bf16x8 ah[2], al[2];
            #pragma unroll
            for (int i = 0; i < 2; ++i) {
                const int row = wm * 32 + i * 16 + (lane & 15);
                const int off = row * (BK * 2) + (kb ^ ((row & 7) << 4));
                ah[i] = *reinterpret_cast<const bf16x8*>(
                            reinterpret_cast<const char*>(h_hi) + off);
                al[i] = *reinterpret_cast<const bf16x8*>(
                            reinterpret_cast<const char*>(h_lo) + off);
            }
            #pragma unroll
            for (int n = 0; n < 4; ++n) {
                const int row = wn * 64 + n * 16 + (lane & 15);
                const int off = row * (BK * 2) + (kb ^ ((row & 7) << 4));
                const bf16x8 bh = *reinterpret_cast<const bf16x8*>(
                            reinterpret_cast<const char*>(w_hi) + off);
                const bf16x8 bl = *reinterpret_cast<const bf16x8*>(
                            reinterpret_cast<const char*>(w_lo) + off);
                #pragma unroll
                for (int i = 0; i < 2; ++i) {
                    acc[i][n] = __builtin_amdgcn_mfma_f32_16x16x32_bf16(ah[i], bh, acc[i][n], 0, 0, 0);
                    acc[i][n] = __builtin_amdgcn_mfma_f32_16x16x32_bf16(ah[i], bl, acc[i][n], 0, 0, 0);
                    acc[i][n] = __builtin_amdgcn_mfma_f32_16x16x32_bf16(al[i], bh, acc[i][n], 0, 0, 0);
                }
            }
        }
    };

    load_chunk(0);
    store_chunk();
    __syncthreads();
    for (int t = 0; t < 4; ++t) {
        if (t < 3) load_chunk((t + 1) * BK);
        compute();
        __syncthreads();
        if (t < 3) { store_chunk(); __syncthreads(); }
    }

    float bias[4];
    int   cols[4];
    #pragma unroll
    for (int n = 0; n < 4; ++n) {
        const int c = v0 + wn * 64 + n * 16 + (lane & 15);
        cols[n] = c;
        bias[n] = (c < V) ? b_out[c] : 0.f;
    }
    const int rbase = b0 + wm * 32 + (lane >> 4) * 4;
    #pragma unroll
    for (int i = 0; i < 2; ++i) {
        #pragma unroll
        for (int r = 0; r < 4; ++r) {
            const int row = rbase + i * 16 + r;
            float* dst = logit + (size_t)row * V;
            #pragma unroll
            for (int n = 0; n < 4; ++n) {
                if (cols[n] < V)
                    dst[cols[n]] = tanhf(acc[i][n][r] + bias[n]);
            }
        }
    }
}

// ---------------------------------------------------------------------------
extern "C" void kernel_launch(void* const* d_in, const int* in_sizes, int n_in,
                              void* d_out, int out_size, void* d_ws, size_t ws_size,
                              hipStream_t stream) {
    const int*   input  = (const int*)  d_in[0];
    // d_in[1] = target (unused by forward)
    const float* hidden = (const float*)d_in[2];
    const float* w_ih   = (const float*)d_in[3];
    const float* w_hh   = (const float*)d_in[4];
    const float* b_ih   = (const float*)d_in[5];
    const float* b_hh   = (const float*)d_in[6];
    const float* w_out  = (const float*)d_in[7];
    const float* b_out  = (const float*)d_in[8];

    float* out   = (float*)d_out;
    float* logit = out;                      // first B*V floats
    float* h_new = out + (size_t)B * V;      // then L*B*H floats (L=1)

    const size_t nh = (size_t)B * H;                          // 131,072
    const size_t needed = 2 * nh * sizeof(unsigned short);    // 512 KB

    if (ws_size >= needed) {
        unsigned short* hhi = (unsigned short*)d_ws;
        unsigned short* hlo = hhi + nh;

        gru_cell_v3<<<256, 256, 0, stream>>>(input, hidden, w_ih, w_hh,
                                             b_ih, b_hh, h_new, hhi, hlo);
        out_gemm_v13<<<NVB * NBB, 256, 0, stream>>>(w_out, hhi, hlo,
                                                    b_out, logit);
    } else {
        gru_cell_v3<<<256, 256, 0, stream>>>(input, hidden, w_ih, w_hh,
                                             b_ih, b_hh, h_new,
                                             nullptr, nullptr);
        out_gemm_mfma_reg<<<NVB * NBB, 256, 0, stream>>>(h_new, w_out,
                                                         b_out, logit);
    }
}